// Round 5
// baseline (393.571 us; speedup 1.0000x reference)
//
#include <hip/hip_runtime.h>

// Problem: B=4, N=512, RBF=32, F=16
// image   (B,N,N,32) f32   d_in[0]
// vectors (B,N,N,3)  f32   d_in[1]
// feat0   (B,N,16,1) f32   d_in[2]
// feat1   (B,N,16,3) f32   d_in[3]
// W00,b00,W01,b01,W10,b10,W11,b11  d_in[4..11]
// out: out1(B,N,16,1) | out2(B,N,16,3) | out3(B,N,16,3) | out4(B,N,16,1) | out5(B,N,16,3)
//
// Round 5: round-2 structure (known good: VGPR 56, no spill, 85us) with
//  - __launch_bounds__(256,8): 8 blocks/CU (grid is exactly 8*256), double
//    residency; TLP instead of the manual banking that spilled in r3/r4.
//  - biases folded into MFMA accumulator init (kills 16 VALU adds/tile)
//  - vectors loaded as 3x float4 (lane's 4 consecutive b's = 12 contiguous
//    aligned floats)

typedef __attribute__((ext_vector_type(8))) short short8;
typedef __attribute__((ext_vector_type(4))) float f32x4;

#define EPS2 1e-14f

static __device__ __forceinline__ short f2bf(float x) {
    unsigned int u = __float_as_uint(x);
    unsigned int r = (u + 0x7FFFu + ((u >> 16) & 1u)) >> 16;   // RNE
    return (short)r;
}

__global__ __launch_bounds__(256, 8) void conv_mfma_occ_kernel(
    const float* __restrict__ image,
    const float* __restrict__ vectors,
    const float* __restrict__ feat0,
    const float* __restrict__ feat1,
    const float* __restrict__ W00, const float* __restrict__ b00,
    const float* __restrict__ W01, const float* __restrict__ b01,
    const float* __restrict__ W10, const float* __restrict__ b10,
    const float* __restrict__ W11, const float* __restrict__ b11,
    float* __restrict__ out)
{
    __shared__ float red[4][16][12];     // [wave][f][comp(11 pad 12)]

    const int t    = threadIdx.x;
    const int wave = t >> 6;
    const int lane = t & 63;
    const int f    = lane & 15;          // B col / D col
    const int g    = lane >> 4;          // k-group (A/B), row-group (D)
    const int ma   = blockIdx.x;         // m*512 + a
    const int m    = ma >> 9;

    // ---- weight fragments (VGPR-resident, once per block) ----
    short8 wf0, wf1, wf2, wf3;
    float bias0, bias1, bias2, bias3;
    {
        #pragma unroll
        for (int j = 0; j < 8; ++j) {
            const int k = g * 8 + j;
            wf0[j] = f2bf(W00[k * 16 + f]);
            wf1[j] = f2bf(W01[k * 16 + f]);
            wf2[j] = f2bf(W10[k * 16 + f]);
            wf3[j] = f2bf(W11[k * 16 + f]);
        }
        bias0 = b00[f]; bias1 = b01[f]; bias2 = b10[f]; bias3 = b11[f];
    }

    const float* imgbase = image   + (size_t)ma * (512 * 32);
    const float* vecbase = vectors + (size_t)ma * (512 * 3);
    const float* f0base  = feat0   + (size_t)m  * (512 * 16);
    const float* f1base  = feat1   + (size_t)m  * (512 * 16 * 3);

    float acc1 = 0.f, acc4 = 0.f;
    float acc2x = 0.f, acc2y = 0.f, acc2z = 0.f;
    float acc3x = 0.f, acc3y = 0.f, acc3z = 0.f;
    float acc5x = 0.f, acc5y = 0.f, acc5z = 0.f;

    const int bbase = wave * 128;        // wave's b range: [bbase, bbase+128)

#define TAIL(R00, R01, R10, R11, VX, VY, VZ, F0V, U0, U1, U2) { \
    const float vx_ = (VX), vy_ = (VY), vz_ = (VZ); \
    const float n2_ = vx_ * vx_ + vy_ * vy_ + vz_ * vz_; \
    const bool keep_ = n2_ >= EPS2; \
    const float r00_ = (R00); \
    const float r01_ = keep_ ? (R01) : 0.f; \
    const float r10_ = (R10); \
    const float r11_ = keep_ ? (R11) : 0.f; \
    const float f0v_ = (F0V); \
    const float u0_ = (U0), u1_ = (U1), u2_ = (U2); \
    acc1 = fmaf(r00_, f0v_, acc1); \
    const float t01_ = r01_ * f0v_; \
    acc2x = fmaf(t01_, vx_, acc2x); \
    acc2y = fmaf(t01_, vy_, acc2y); \
    acc2z = fmaf(t01_, vz_, acc2z); \
    acc3x = fmaf(r10_, u0_, acc3x); \
    acc3y = fmaf(r10_, u1_, acc3y); \
    acc3z = fmaf(r10_, u2_, acc3z); \
    const float dd_ = fmaf(vx_, u0_, fmaf(vy_, u1_, vz_ * u2_)); \
    acc4 = fmaf(r11_, dd_, acc4); \
    acc5x = fmaf(r11_, vy_ * u2_ - vz_ * u1_, acc5x); \
    acc5y = fmaf(r11_, vz_ * u0_ - vx_ * u2_, acc5y); \
    acc5z = fmaf(r11_, vx_ * u1_ - vy_ * u0_, acc5z); \
}

    for (int tt = 0; tt < 8; ++tt) {
        const int b0 = bbase + tt * 16;

        // ---- A fragment: image[b0 + f][g*8 .. g*8+8) ----
        const float* arow = imgbase + (size_t)(b0 + f) * 32 + g * 8;
        const float4 a0 = *(const float4*)(arow);
        const float4 a1 = *(const float4*)(arow + 4);

        // ---- tail operands: lane owns b = b0 + 4*g + reg ----
        const int bb = b0 + 4 * g;
        const float* vp = vecbase + bb * 3;          // 48B-aligned
        const float4 V0 = *(const float4*)(vp);
        const float4 V1 = *(const float4*)(vp + 4);
        const float4 V2 = *(const float4*)(vp + 8);
        const float* f0p = f0base + bb * 16 + f;
        const float F0a = f0p[0], F0b = f0p[16], F0c = f0p[32], F0d = f0p[48];
        const float* f1p = f1base + (size_t)(bb * 16 + f) * 3;
        const float P00 = f1p[0],   P01 = f1p[1],   P02 = f1p[2];
        const float P10 = f1p[48],  P11 = f1p[49],  P12 = f1p[50];
        const float P20 = f1p[96],  P21 = f1p[97],  P22 = f1p[98];
        const float P30 = f1p[144], P31 = f1p[145], P32 = f1p[146];

        short8 af;
        af[0] = f2bf(a0.x); af[1] = f2bf(a0.y);
        af[2] = f2bf(a0.z); af[3] = f2bf(a0.w);
        af[4] = f2bf(a1.x); af[5] = f2bf(a1.y);
        af[6] = f2bf(a1.z); af[7] = f2bf(a1.w);

        // bias folded into accumulator init
        f32x4 d0 = {bias0, bias0, bias0, bias0};
        f32x4 d1 = {bias1, bias1, bias1, bias1};
        f32x4 d2 = {bias2, bias2, bias2, bias2};
        f32x4 d3 = {bias3, bias3, bias3, bias3};
        d0 = __builtin_amdgcn_mfma_f32_16x16x32_bf16(af, wf0, d0, 0, 0, 0);
        d1 = __builtin_amdgcn_mfma_f32_16x16x32_bf16(af, wf1, d1, 0, 0, 0);
        d2 = __builtin_amdgcn_mfma_f32_16x16x32_bf16(af, wf2, d2, 0, 0, 0);
        d3 = __builtin_amdgcn_mfma_f32_16x16x32_bf16(af, wf3, d3, 0, 0, 0);

        TAIL(d0[0], d1[0], d2[0], d3[0], V0.x, V0.y, V0.z, F0a, P00, P01, P02)
        TAIL(d0[1], d1[1], d2[1], d3[1], V0.w, V1.x, V1.y, F0b, P10, P11, P12)
        TAIL(d0[2], d1[2], d2[2], d3[2], V1.z, V1.w, V2.x, F0c, P20, P21, P22)
        TAIL(d0[3], d1[3], d2[3], d3[3], V2.y, V2.z, V2.w, F0d, P30, P31, P32)
    }
#undef TAIL

    // ---- in-wave reduce over the 4 lane-groups sharing f ----
    #define WRED(x) x += __shfl_xor(x, 16); x += __shfl_xor(x, 32);
    WRED(acc1)  WRED(acc2x) WRED(acc2y) WRED(acc2z)
    WRED(acc3x) WRED(acc3y) WRED(acc3z) WRED(acc4)
    WRED(acc5x) WRED(acc5y) WRED(acc5z)
    #undef WRED

    if (lane < 16) {
        red[wave][f][0]  = acc1;
        red[wave][f][1]  = acc2x;
        red[wave][f][2]  = acc2y;
        red[wave][f][3]  = acc2z;
        red[wave][f][4]  = acc3x;
        red[wave][f][5]  = acc3y;
        red[wave][f][6]  = acc3z;
        red[wave][f][7]  = acc4;
        red[wave][f][8]  = acc5x;
        red[wave][f][9]  = acc5y;
        red[wave][f][10] = acc5z;
    }
    __syncthreads();

    if (t < 176) {
        const int ff = t / 11;
        const int comp = t % 11;
        float s = red[0][ff][comp] + red[1][ff][comp]
                + red[2][ff][comp] + red[3][ff][comp];

        const size_t base16 = (size_t)ma * 16 + ff;
        const size_t base48 = base16 * 3;
        if (comp == 0)      out[base16] = s;
        else if (comp < 4)  out[32768  + base48 + (comp - 1)] = s;
        else if (comp < 7)  out[131072 + base48 + (comp - 4)] = s;
        else if (comp == 7) out[229376 + base16] = s;
        else                out[262144 + base48 + (comp - 8)] = s;
    }
}

extern "C" void kernel_launch(void* const* d_in, const int* in_sizes, int n_in,
                              void* d_out, int out_size, void* d_ws, size_t ws_size,
                              hipStream_t stream) {
    const float* image   = (const float*)d_in[0];
    const float* vectors = (const float*)d_in[1];
    const float* feat0   = (const float*)d_in[2];
    const float* feat1   = (const float*)d_in[3];
    const float* W00 = (const float*)d_in[4];
    const float* b00 = (const float*)d_in[5];
    const float* W01 = (const float*)d_in[6];
    const float* b01 = (const float*)d_in[7];
    const float* W10 = (const float*)d_in[8];
    const float* b10 = (const float*)d_in[9];
    const float* W11 = (const float*)d_in[10];
    const float* b11 = (const float*)d_in[11];
    float* out = (float*)d_out;

    conv_mfma_occ_kernel<<<4 * 512, 256, 0, stream>>>(
        image, vectors, feat0, feat1,
        W00, b00, W01, b01, W10, b10, W11, b11, out);
}

// Round 6
// 225.969 us; speedup vs baseline: 1.7417x; 1.7417x over previous
//
#include <hip/hip_runtime.h>
#include <hip/hip_bf16.h>

// Problem: B=4, N=512, RBF=32, F=16
// image   (B,N,N,32) f32   d_in[0]
// vectors (B,N,N,3)  f32   d_in[1]
// feat0   (B,N,16,1) f32   d_in[2]
// feat1   (B,N,16,3) f32   d_in[3]
// W00,b00,W01,b01,W10,b10,W11,b11  d_in[4..11]
// out: out1(B,N,16,1) | out2(B,N,16,3) | out3(B,N,16,3) | out4(B,N,16,1) | out5(B,N,16,3)
//
// Round 6: round-2 skeleton verbatim (85us, VGPR 56, zero spill) with ONLY
// load-count reduction (30 -> 13 VMEM per tile):
//   - vectors: 3x float4 (lane b-base multiple of 4 -> 48B aligned)
//   - feat1:   4x float3 (dwordx3)
//   - bias folded into MFMA C-init (r5, harmless)
//   - __float2bfloat16 instead of hand-rolled RNE (compiler emits cvt_pk)
// No manual banking (r3/r4 spilled), no occupancy forcing (r5 spilled).

typedef __attribute__((ext_vector_type(8))) short short8;
typedef __attribute__((ext_vector_type(4))) float f32x4;

#define EPS2 1e-14f

static __device__ __forceinline__ short f2bf(float x) {
    __hip_bfloat16 h = __float2bfloat16(x);
    return *reinterpret_cast<short*>(&h);
}

__global__ __launch_bounds__(256, 4) void conv_mfma_vec_kernel(
    const float* __restrict__ image,
    const float* __restrict__ vectors,
    const float* __restrict__ feat0,
    const float* __restrict__ feat1,
    const float* __restrict__ W00, const float* __restrict__ b00,
    const float* __restrict__ W01, const float* __restrict__ b01,
    const float* __restrict__ W10, const float* __restrict__ b10,
    const float* __restrict__ W11, const float* __restrict__ b11,
    float* __restrict__ out)
{
    __shared__ float red[4][16][12];     // [wave][f][comp(11 pad 12)]

    const int t    = threadIdx.x;
    const int wave = t >> 6;
    const int lane = t & 63;
    const int f    = lane & 15;          // B col / D col
    const int g    = lane >> 4;          // k-group (A/B), row-group (D)
    const int ma   = blockIdx.x;         // m*512 + a
    const int m    = ma >> 9;

    // ---- weight fragments (VGPR-resident, once per block) ----
    short8 wf0, wf1, wf2, wf3;
    float bias0, bias1, bias2, bias3;
    {
        #pragma unroll
        for (int j = 0; j < 8; ++j) {
            const int k = g * 8 + j;
            wf0[j] = f2bf(W00[k * 16 + f]);
            wf1[j] = f2bf(W01[k * 16 + f]);
            wf2[j] = f2bf(W10[k * 16 + f]);
            wf3[j] = f2bf(W11[k * 16 + f]);
        }
        bias0 = b00[f]; bias1 = b01[f]; bias2 = b10[f]; bias3 = b11[f];
    }

    const float* imgbase = image   + (size_t)ma * (512 * 32);
    const float* vecbase = vectors + (size_t)ma * (512 * 3);
    const float* f0base  = feat0   + (size_t)m  * (512 * 16);
    const float* f1base  = feat1   + (size_t)m  * (512 * 16 * 3);

    float acc1 = 0.f, acc4 = 0.f;
    float acc2x = 0.f, acc2y = 0.f, acc2z = 0.f;
    float acc3x = 0.f, acc3y = 0.f, acc3z = 0.f;
    float acc5x = 0.f, acc5y = 0.f, acc5z = 0.f;

    const int bbase = wave * 128;        // wave's b range: [bbase, bbase+128)

#define TAIL(R00, R01, R10, R11, VX, VY, VZ, F0V, U0, U1, U2) { \
    const float vx_ = (VX), vy_ = (VY), vz_ = (VZ); \
    const float n2_ = vx_ * vx_ + vy_ * vy_ + vz_ * vz_; \
    const bool keep_ = n2_ >= EPS2; \
    const float r00_ = (R00); \
    const float r01_ = keep_ ? (R01) : 0.f; \
    const float r10_ = (R10); \
    const float r11_ = keep_ ? (R11) : 0.f; \
    const float f0v_ = (F0V); \
    const float u0_ = (U0), u1_ = (U1), u2_ = (U2); \
    acc1 = fmaf(r00_, f0v_, acc1); \
    const float t01_ = r01_ * f0v_; \
    acc2x = fmaf(t01_, vx_, acc2x); \
    acc2y = fmaf(t01_, vy_, acc2y); \
    acc2z = fmaf(t01_, vz_, acc2z); \
    acc3x = fmaf(r10_, u0_, acc3x); \
    acc3y = fmaf(r10_, u1_, acc3y); \
    acc3z = fmaf(r10_, u2_, acc3z); \
    const float dd_ = fmaf(vx_, u0_, fmaf(vy_, u1_, vz_ * u2_)); \
    acc4 = fmaf(r11_, dd_, acc4); \
    acc5x = fmaf(r11_, vy_ * u2_ - vz_ * u1_, acc5x); \
    acc5y = fmaf(r11_, vz_ * u0_ - vx_ * u2_, acc5y); \
    acc5z = fmaf(r11_, vx_ * u1_ - vy_ * u0_, acc5z); \
}

    for (int tt = 0; tt < 8; ++tt) {
        const int b0 = bbase + tt * 16;

        // ---- A fragment: image[b0 + f][g*8 .. g*8+8) ----  (2x float4)
        const float* arow = imgbase + (size_t)(b0 + f) * 32 + g * 8;
        const float4 a0 = *(const float4*)(arow);
        const float4 a1 = *(const float4*)(arow + 4);

        // ---- tail operands: lane owns b = b0 + 4*g + reg ----
        const int bb = b0 + 4 * g;
        const float* vp = vecbase + bb * 3;          // 48B-aligned
        const float4 V0 = *(const float4*)(vp);      // 3x float4
        const float4 V1 = *(const float4*)(vp + 4);
        const float4 V2 = *(const float4*)(vp + 8);
        const float* f0p = f0base + bb * 16 + f;
        const float F0a = f0p[0], F0b = f0p[16], F0c = f0p[32], F0d = f0p[48];
        const float* f1p = f1base + (size_t)(bb * 16 + f) * 3;
        const float3 U_0 = *(const float3*)(f1p);        // 4x float3
        const float3 U_1 = *(const float3*)(f1p + 48);
        const float3 U_2 = *(const float3*)(f1p + 96);
        const float3 U_3 = *(const float3*)(f1p + 144);

        short8 af;
        af[0] = f2bf(a0.x); af[1] = f2bf(a0.y);
        af[2] = f2bf(a0.z); af[3] = f2bf(a0.w);
        af[4] = f2bf(a1.x); af[5] = f2bf(a1.y);
        af[6] = f2bf(a1.z); af[7] = f2bf(a1.w);

        // bias folded into accumulator init
        f32x4 d0 = {bias0, bias0, bias0, bias0};
        f32x4 d1 = {bias1, bias1, bias1, bias1};
        f32x4 d2 = {bias2, bias2, bias2, bias2};
        f32x4 d3 = {bias3, bias3, bias3, bias3};
        d0 = __builtin_amdgcn_mfma_f32_16x16x32_bf16(af, wf0, d0, 0, 0, 0);
        d1 = __builtin_amdgcn_mfma_f32_16x16x32_bf16(af, wf1, d1, 0, 0, 0);
        d2 = __builtin_amdgcn_mfma_f32_16x16x32_bf16(af, wf2, d2, 0, 0, 0);
        d3 = __builtin_amdgcn_mfma_f32_16x16x32_bf16(af, wf3, d3, 0, 0, 0);

        TAIL(d0[0], d1[0], d2[0], d3[0], V0.x, V0.y, V0.z, F0a, U_0.x, U_0.y, U_0.z)
        TAIL(d0[1], d1[1], d2[1], d3[1], V0.w, V1.x, V1.y, F0b, U_1.x, U_1.y, U_1.z)
        TAIL(d0[2], d1[2], d2[2], d3[2], V1.z, V1.w, V2.x, F0c, U_2.x, U_2.y, U_2.z)
        TAIL(d0[3], d1[3], d2[3], d3[3], V2.y, V2.z, V2.w, F0d, U_3.x, U_3.y, U_3.z)
    }
#undef TAIL

    // ---- in-wave reduce over the 4 lane-groups sharing f ----
    #define WRED(x) x += __shfl_xor(x, 16); x += __shfl_xor(x, 32);
    WRED(acc1)  WRED(acc2x) WRED(acc2y) WRED(acc2z)
    WRED(acc3x) WRED(acc3y) WRED(acc3z) WRED(acc4)
    WRED(acc5x) WRED(acc5y) WRED(acc5z)
    #undef WRED

    if (lane < 16) {
        red[wave][f][0]  = acc1;
        red[wave][f][1]  = acc2x;
        red[wave][f][2]  = acc2y;
        red[wave][f][3]  = acc2z;
        red[wave][f][4]  = acc3x;
        red[wave][f][5]  = acc3y;
        red[wave][f][6]  = acc3z;
        red[wave][f][7]  = acc4;
        red[wave][f][8]  = acc5x;
        red[wave][f][9]  = acc5y;
        red[wave][f][10] = acc5z;
    }
    __syncthreads();

    if (t < 176) {
        const int ff = t / 11;
        const int comp = t % 11;
        float s = red[0][ff][comp] + red[1][ff][comp]
                + red[2][ff][comp] + red[3][ff][comp];

        const size_t base16 = (size_t)ma * 16 + ff;
        const size_t base48 = base16 * 3;
        if (comp == 0)      out[base16] = s;
        else if (comp < 4)  out[32768  + base48 + (comp - 1)] = s;
        else if (comp < 7)  out[131072 + base48 + (comp - 4)] = s;
        else if (comp == 7) out[229376 + base16] = s;
        else                out[262144 + base48 + (comp - 8)] = s;
    }
}

extern "C" void kernel_launch(void* const* d_in, const int* in_sizes, int n_in,
                              void* d_out, int out_size, void* d_ws, size_t ws_size,
                              hipStream_t stream) {
    const float* image   = (const float*)d_in[0];
    const float* vectors = (const float*)d_in[1];
    const float* feat0   = (const float*)d_in[2];
    const float* feat1   = (const float*)d_in[3];
    const float* W00 = (const float*)d_in[4];
    const float* b00 = (const float*)d_in[5];
    const float* W01 = (const float*)d_in[6];
    const float* b01 = (const float*)d_in[7];
    const float* W10 = (const float*)d_in[8];
    const float* b10 = (const float*)d_in[9];
    const float* W11 = (const float*)d_in[10];
    const float* b11 = (const float*)d_in[11];
    float* out = (float*)d_out;

    conv_mfma_vec_kernel<<<4 * 512, 256, 0, stream>>>(
        image, vectors, feat0, feat1,
        W00, b00, W01, b01, W10, b10, W11, b11, out);
}